// Round 7
// baseline (385.108 us; speedup 1.0000x reference)
//
#include <hip/hip_runtime.h>
#include <hip/hip_bf16.h>
#include <cstdint>
#include <cstddef>

// Causal self-attention, B=2 S=2048 E=1024 H=16 D=64.
// Inputs fp32, output fp32, ws intermediates bf16.
// Round 6: barrier-free MFMA attention. V is pre-transposed to [b][h][d][s]
// by a tiny vtrans kernel (scratch = first 8.4MB of d_out, later fully
// overwritten by the output projection); PV B-frags load straight from
// global (L1/L2-resident), killing the 7.5M-conflict LDS transpose staging.
// GEMMs unchanged from round 5.

#define B_  2
#define S_  2048
#define E_  1024
#define NH_ 16
#define DH_ 64
#define M_  (B_*S_)      // 4096
#define F_  (NH_*DH_)    // 1024

typedef unsigned short u16;
typedef short short8 __attribute__((ext_vector_type(8)));
typedef float f32x4  __attribute__((ext_vector_type(4)));

__device__ __forceinline__ float bf2f(u16 u) {
    union { unsigned int i; float f; } c; c.i = ((unsigned int)u) << 16; return c.f;
}
__device__ __forceinline__ u16 f2bf(float f) {
    union { float f; unsigned int i; } c; c.f = f;
    unsigned int x = c.i;
    x += 0x7fffu + ((x >> 16) & 1u);   // RNE
    return (u16)(x >> 16);
}

// ---------------------------------------------------------------------------
// MFMA GEMM (unchanged from round 5). 128x128 tile, BK=64, 4 waves.
// MODE 0: A = x fp32; out bf16 scattered to [b][h][s][d]; grid.z = q/k/v.
// MODE 2: A = attn-O bf16 [b][h][s][d] (gather); out fp32 row-major.
// ---------------------------------------------------------------------------
template<int MODE>
__global__ __launch_bounds__(256)
void mfma_gemm(const void* __restrict__ Araw,
               const float* __restrict__ W0, const float* __restrict__ W1,
               const float* __restrict__ W2,
               void* __restrict__ Out0, void* __restrict__ Out1,
               void* __restrict__ Out2)
{
    __shared__ __align__(16) char lds[32768];
    char* lA = lds;            // 128 rows * 128 B
    char* lB = lds + 16384;    // 128 n    * 128 B

    const int tid = threadIdx.x;
    const int lane = tid & 63;
    const int w    = tid >> 6;
    const int wr   = w >> 1, wc = w & 1;
    const int g    = lane >> 4;
    const int q15  = lane & 15;
    const int bx   = blockIdx.x;
    const int by   = blockIdx.y;
    const int z    = (MODE == 0) ? blockIdx.z : 0;

    const float* W   = (z == 0) ? W0 : (z == 1) ? W1 : W2;
    void*        Out = (z == 0) ? Out0 : (z == 1) ? Out1 : Out2;

    const int sArow = tid >> 1;
    const int sAseg = (tid & 1) * 32;
    const int sBkb  = (tid >> 2) & 7;
    const int sBcb  = (tid >> 5) * 4 + (tid & 3);

    f32x4 acc[4][4];
    #pragma unroll
    for (int i = 0; i < 4; ++i)
        #pragma unroll
        for (int j = 0; j < 4; ++j) acc[i][j] = (f32x4){0.f,0.f,0.f,0.f};

    float4 pa[8];
    short8 pa2[4];
    float4 pb[8];

    const int aRow = by*128 + sArow;
    const int ab   = aRow >> 11, as = aRow & (S_-1);

    auto LOADA = [&](int k0) {
        if (MODE == 0) {
            const float* ap = (const float*)Araw + (size_t)aRow * E_ + k0 + sAseg;
            #pragma unroll
            for (int u = 0; u < 8; ++u) pa[u] = ((const float4*)ap)[u];
        } else {
            int h = k0 >> 6;
            const u16* ap = (const u16*)Araw +
                (((size_t)ab*NH_ + h)*S_ + as)*DH_ + sAseg;
            #pragma unroll
            for (int u = 0; u < 4; ++u) pa2[u] = ((const short8*)ap)[u];
        }
    };
    auto LOADB = [&](int k0) {
        const float* bp = W + (size_t)(k0 + sBkb*8) * F_ + bx*128 + sBcb*4;
        #pragma unroll
        for (int j = 0; j < 8; ++j) pb[j] = *(const float4*)(bp + (size_t)j * F_);
    };
    auto WRITEA = [&]() {
        #pragma unroll
        for (int c = 0; c < 4; ++c) {
            short8 ch;
            if (MODE == 0) {
                const float* f0 = (const float*)&pa[2*c];
                #pragma unroll
                for (int j = 0; j < 8; ++j) ((u16*)&ch)[j] = f2bf(f0[j]);
            } else ch = pa2[c];
            *(short8*)(lA + sArow*128 + ((sAseg*2 + 16*c) ^ ((sArow&7)<<4))) = ch;
        }
    };
    auto WRITEB = [&]() {
        #pragma unroll
        for (int c = 0; c < 4; ++c) {
            short8 bs;
            #pragma unroll
            for (int j = 0; j < 8; ++j)
                ((u16*)&bs)[j] = f2bf(((const float*)&pb[j])[c]);
            int n = sBcb*4 + c;
            *(short8*)(lB + n*128 + ((16*sBkb) ^ ((n&7)<<4))) = bs;
        }
    };

    LOADA(0); LOADB(0);

    for (int it = 0; it < E_/64; ++it) {
        __syncthreads();
        WRITEA(); WRITEB();
        __syncthreads();
        if (it + 1 < E_/64) { LOADA((it+1)*64); LOADB((it+1)*64); }
        #pragma unroll
        for (int s = 0; s < 2; ++s) {
            short8 af[4], bfr[4];
            #pragma unroll
            for (int mt = 0; mt < 4; ++mt) {
                int row = wr*64 + mt*16 + q15;
                af[mt] = *(const short8*)(lA + row*128 + ((s*64 + 16*g) ^ ((row&7)<<4)));
            }
            #pragma unroll
            for (int nt = 0; nt < 4; ++nt) {
                int n = wc*64 + nt*16 + q15;
                bfr[nt] = *(const short8*)(lB + n*128 + ((s*64 + 16*g) ^ ((n&7)<<4)));
            }
            #pragma unroll
            for (int mt = 0; mt < 4; ++mt)
                #pragma unroll
                for (int nt = 0; nt < 4; ++nt)
                    acc[mt][nt] = __builtin_amdgcn_mfma_f32_16x16x32_bf16(
                        af[mt], bfr[nt], acc[mt][nt], 0, 0, 0);
        }
    }

    #pragma unroll
    for (int mt = 0; mt < 4; ++mt) {
        #pragma unroll
        for (int r = 0; r < 4; ++r) {
            int grow = by*128 + wr*64 + mt*16 + 4*g + r;
            if (MODE == 0) {
                int bb = grow >> 11, ss = grow & (S_-1);
                #pragma unroll
                for (int nt = 0; nt < 4; ++nt) {
                    int n = bx*128 + wc*64 + nt*16 + q15;
                    int hh = n >> 6, dd = n & 63;
                    ((u16*)Out)[(((size_t)bb*NH_ + hh)*S_ + ss)*DH_ + dd] =
                        f2bf(acc[mt][nt][r]);
                }
            } else {
                #pragma unroll
                for (int nt = 0; nt < 4; ++nt) {
                    int n = bx*128 + wc*64 + nt*16 + q15;
                    ((float*)Out)[(size_t)grow * F_ + n] = acc[mt][nt][r];
                }
            }
        }
    }
}

// ---------------------------------------------------------------------------
// V transpose: [b][h][s][d] -> Vt [b][h][d][s]. One block per (bh, 64-s tile).
// ---------------------------------------------------------------------------
__global__ __launch_bounds__(256)
void vtrans(const u16* __restrict__ V, u16* __restrict__ Vt)
{
    __shared__ u16 t[64][66];   // pitch 66 u16: column reads ~4-way max
    const int tid = threadIdx.x;
    const int st  = blockIdx.x;   // s tile 0..31
    const int bh  = blockIdx.y;   // 0..31

    {
        int s = tid >> 2, dseg = (tid & 3) * 16;
        const u16* src = V + ((size_t)bh*S_ + st*64 + s)*DH_ + dseg;
        short8 a = ((const short8*)src)[0];
        short8 b = ((const short8*)src)[1];
        *(short8*)&t[s][dseg]     = a;
        *(short8*)&t[s][dseg + 8] = b;
    }
    __syncthreads();
    {
        int d = tid >> 2, sseg = (tid & 3) * 16;
        short8 o0, o1;
        #pragma unroll
        for (int i = 0; i < 8; ++i) ((u16*)&o0)[i] = t[sseg + i][d];
        #pragma unroll
        for (int i = 0; i < 8; ++i) ((u16*)&o1)[i] = t[sseg + 8 + i][d];
        u16* dst = Vt + ((size_t)bh*DH_ + d)*S_ + st*64 + sseg;
        ((short8*)dst)[0] = o0;
        ((short8*)dst)[1] = o1;
    }
}

// ---------------------------------------------------------------------------
// Barrier-free MFMA flash attention. Q,K: [b][h][s][d]; Vt: [b][h][d][s].
// O overwrites this block's own Q rows. Per-wave P LDS only (no syncthreads).
// ---------------------------------------------------------------------------
__global__ __launch_bounds__(256)
void attn_v2(const u16* Q, const u16* __restrict__ K,
             const u16* __restrict__ Vt, u16* O)
{
    __shared__ u16 pl[4][16*64];    // per-wave P [q][key], swizzled

    const int tid  = threadIdx.x;
    const int lane = tid & 63;
    const int w    = tid >> 6;
    const int g    = lane >> 4;
    const int q15  = lane & 15;

    const int blk = blockIdx.x;
    const int tq  = blk & 31;
    const int qg  = (tq & 1) ? (31 - (tq >> 1)) : (tq >> 1);
    const int bh  = blk >> 5;
    const int q0  = qg * 64;

    const u16* Kb  = K  + (size_t)bh * S_ * DH_;
    const u16* Vtb = Vt + (size_t)bh * DH_ * S_;

    short8 qf0, qf1;
    {
        const u16* Qp = Q + ((size_t)bh * S_ + q0 + w*16 + q15) * DH_ + g*8;
        qf0 = *(const short8*)(Qp);
        qf1 = *(const short8*)(Qp + 32);
    }

    f32x4 o[4];
    #pragma unroll
    for (int dt = 0; dt < 4; ++dt) o[dt] = (f32x4){0.f,0.f,0.f,0.f};
    float mrow = -1e30f, lrow = 0.f;

    char* plw = (char*)&pl[w][0];

    for (int kt = 0; kt <= qg; ++kt) {
        // ---- QK^T: K frags from global (L1/L2), Q frags hoisted ----
        float p[16];
        {
            const u16* Kp = Kb + (size_t)(kt*64 + q15) * DH_ + g*8;
            #pragma unroll
            for (int t = 0; t < 4; ++t) {
                f32x4 st = (f32x4){0.f,0.f,0.f,0.f};
                short8 kf0 = *(const short8*)(Kp + (size_t)t*16*DH_);
                short8 kf1 = *(const short8*)(Kp + (size_t)t*16*DH_ + 32);
                st = __builtin_amdgcn_mfma_f32_16x16x32_bf16(kf0, qf0, st, 0, 0, 0);
                st = __builtin_amdgcn_mfma_f32_16x16x32_bf16(kf1, qf1, st, 0, 0, 0);
                #pragma unroll
                for (int r = 0; r < 4; ++r) p[t*4+r] = st[r] * 0.125f;
            }
        }

        // causal mask (diagonal tile only): key' = 16t+4g+r vs q' = w*16+q15
        if (kt == qg) {
            #pragma unroll
            for (int t = 0; t < 4; ++t)
                #pragma unroll
                for (int r = 0; r < 4; ++r)
                    if (16*t + 4*g + r > w*16 + q15) p[t*4+r] = -1e30f;
        }

        // ---- online softmax (row = q15, spread over lane groups) ----
        float tmax = p[0];
        #pragma unroll
        for (int i = 1; i < 16; ++i) tmax = fmaxf(tmax, p[i]);
        tmax = fmaxf(tmax, __shfl_xor(tmax, 16));
        tmax = fmaxf(tmax, __shfl_xor(tmax, 32));
        float mnew = fmaxf(mrow, tmax);
        float rsc  = __expf(mrow - mnew);
        mrow = mnew;
        float psum = 0.f;
        #pragma unroll
        for (int i = 0; i < 16; ++i) { p[i] = __expf(p[i] - mnew); psum += p[i]; }
        psum += __shfl_xor(psum, 16);
        psum += __shfl_xor(psum, 32);
        lrow = lrow * rsc + psum;

        #pragma unroll
        for (int r = 0; r < 4; ++r) {
            float rr = __shfl(rsc, 4*g + r);
            #pragma unroll
            for (int dt = 0; dt < 4; ++dt) o[dt][r] *= rr;
        }

        // ---- P -> bf16 -> per-wave LDS [q][key], swizzled (in-wave dep) ----
        #pragma unroll
        for (int t = 0; t < 4; ++t) {
            ushort4 pw;
            pw.x = f2bf(p[t*4+0]); pw.y = f2bf(p[t*4+1]);
            pw.z = f2bf(p[t*4+2]); pw.w = f2bf(p[t*4+3]);
            int byte = q15*128 + ((32*t + 8*g) ^ ((q15&7)<<4));
            *(ushort4*)(plw + byte) = pw;
        }

        // ---- PV: V^T frags straight from global ----
        #pragma unroll
        for (int c = 0; c < 2; ++c) {
            int pb = q15*128 + ((64*c + 16*g) ^ ((q15&7)<<4));
            short8 pf = *(const short8*)(plw + pb);
            #pragma unroll
            for (int dt = 0; dt < 4; ++dt) {
                const u16* vp = Vtb + (size_t)(dt*16 + q15) * S_
                                + kt*64 + c*32 + g*8;
                short8 vf = *(const short8*)vp;
                o[dt] = __builtin_amdgcn_mfma_f32_16x16x32_bf16(pf, vf, o[dt], 0, 0, 0);
            }
        }
    }

    // ---- epilogue: /l, write O into own Q bytes [b][h][s][d] ----
    float inv = 1.f / lrow;
    #pragma unroll
    for (int r = 0; r < 4; ++r) {
        float li = __shfl(inv, 4*g + r);
        int qrow = q0 + w*16 + 4*g + r;
        #pragma unroll
        for (int dt = 0; dt < 4; ++dt) {
            O[((size_t)bh * S_ + qrow) * DH_ + dt*16 + q15] = f2bf(o[dt][r] * li);
        }
    }
}

// ---------------------------------------------------------------------------
extern "C" void kernel_launch(void* const* d_in, const int* in_sizes, int n_in,
                              void* d_out, int out_size, void* d_ws, size_t ws_size,
                              hipStream_t stream) {
    (void)in_sizes; (void)n_in; (void)out_size; (void)ws_size;
    const float* x  = (const float*)d_in[0];
    const float* wq = (const float*)d_in[1];
    const float* wk = (const float*)d_in[2];
    const float* wv = (const float*)d_in[3];
    const float* wo = (const float*)d_in[4];

    u16* Qw = (u16*)d_ws;                    // [B][H][S][D] bf16 (O reuses)
    u16* Kw = Qw + (size_t)M_ * F_;
    u16* Vw = Kw + (size_t)M_ * F_;          // ws total 24 MiB
    u16* Vt = (u16*)d_out;                   // scratch: first 8.4 MB of d_out,
                                             // fully overwritten by oproj below

    mfma_gemm<0><<<dim3(F_/128, M_/128, 3), 256, 0, stream>>>(
        (const void*)x, wq, wk, wv, (void*)Qw, (void*)Kw, (void*)Vw);
    vtrans<<<dim3(S_/64, B_*NH_), 256, 0, stream>>>(Vw, Vt);
    attn_v2<<<dim3(B_*NH_*(S_/64)), 256, 0, stream>>>(Qw, Kw, Vt, Qw);
    mfma_gemm<2><<<dim3(F_/128, M_/128, 1), 256, 0, stream>>>(
        (const void*)Qw, wo, wo, wo, d_out, d_out, d_out);
}

// Round 8
// 245.532 us; speedup vs baseline: 1.5685x; 1.5685x over previous
//
#include <hip/hip_runtime.h>
#include <hip/hip_bf16.h>
#include <cstdint>
#include <cstddef>

// Causal self-attention, B=2 S=2048 E=1024 H=16 D=64.
// Inputs fp32, output fp32, ws intermediates bf16.
// Round 7: attention = round-5 LDS structure (swizzled b128 PV reads) with
// staging fixed: V pre-transposed globally (vtrans), V^T tile staged via
// coalesced global reads + 2x ds_write_b128/thread into the same XOR lattice.
// GEMMs + vtrans unchanged.

#define B_  2
#define S_  2048
#define E_  1024
#define NH_ 16
#define DH_ 64
#define M_  (B_*S_)      // 4096
#define F_  (NH_*DH_)    // 1024

typedef unsigned short u16;
typedef short short8 __attribute__((ext_vector_type(8)));
typedef float f32x4  __attribute__((ext_vector_type(4)));

__device__ __forceinline__ float bf2f(u16 u) {
    union { unsigned int i; float f; } c; c.i = ((unsigned int)u) << 16; return c.f;
}
__device__ __forceinline__ u16 f2bf(float f) {
    union { float f; unsigned int i; } c; c.f = f;
    unsigned int x = c.i;
    x += 0x7fffu + ((x >> 16) & 1u);   // RNE
    return (u16)(x >> 16);
}

// ---------------------------------------------------------------------------
// MFMA GEMM (unchanged). 128x128 tile, BK=64, 4 waves.
// ---------------------------------------------------------------------------
template<int MODE>
__global__ __launch_bounds__(256)
void mfma_gemm(const void* __restrict__ Araw,
               const float* __restrict__ W0, const float* __restrict__ W1,
               const float* __restrict__ W2,
               void* __restrict__ Out0, void* __restrict__ Out1,
               void* __restrict__ Out2)
{
    __shared__ __align__(16) char lds[32768];
    char* lA = lds;
    char* lB = lds + 16384;

    const int tid = threadIdx.x;
    const int lane = tid & 63;
    const int w    = tid >> 6;
    const int wr   = w >> 1, wc = w & 1;
    const int g    = lane >> 4;
    const int q15  = lane & 15;
    const int bx   = blockIdx.x;
    const int by   = blockIdx.y;
    const int z    = (MODE == 0) ? blockIdx.z : 0;

    const float* W   = (z == 0) ? W0 : (z == 1) ? W1 : W2;
    void*        Out = (z == 0) ? Out0 : (z == 1) ? Out1 : Out2;

    const int sArow = tid >> 1;
    const int sAseg = (tid & 1) * 32;
    const int sBkb  = (tid >> 2) & 7;
    const int sBcb  = (tid >> 5) * 4 + (tid & 3);

    f32x4 acc[4][4];
    #pragma unroll
    for (int i = 0; i < 4; ++i)
        #pragma unroll
        for (int j = 0; j < 4; ++j) acc[i][j] = (f32x4){0.f,0.f,0.f,0.f};

    float4 pa[8];
    short8 pa2[4];
    float4 pb[8];

    const int aRow = by*128 + sArow;
    const int ab   = aRow >> 11, as = aRow & (S_-1);

    auto LOADA = [&](int k0) {
        if (MODE == 0) {
            const float* ap = (const float*)Araw + (size_t)aRow * E_ + k0 + sAseg;
            #pragma unroll
            for (int u = 0; u < 8; ++u) pa[u] = ((const float4*)ap)[u];
        } else {
            int h = k0 >> 6;
            const u16* ap = (const u16*)Araw +
                (((size_t)ab*NH_ + h)*S_ + as)*DH_ + sAseg;
            #pragma unroll
            for (int u = 0; u < 4; ++u) pa2[u] = ((const short8*)ap)[u];
        }
    };
    auto LOADB = [&](int k0) {
        const float* bp = W + (size_t)(k0 + sBkb*8) * F_ + bx*128 + sBcb*4;
        #pragma unroll
        for (int j = 0; j < 8; ++j) pb[j] = *(const float4*)(bp + (size_t)j * F_);
    };
    auto WRITEA = [&]() {
        #pragma unroll
        for (int c = 0; c < 4; ++c) {
            short8 ch;
            if (MODE == 0) {
                const float* f0 = (const float*)&pa[2*c];
                #pragma unroll
                for (int j = 0; j < 8; ++j) ((u16*)&ch)[j] = f2bf(f0[j]);
            } else ch = pa2[c];
            *(short8*)(lA + sArow*128 + ((sAseg*2 + 16*c) ^ ((sArow&7)<<4))) = ch;
        }
    };
    auto WRITEB = [&]() {
        #pragma unroll
        for (int c = 0; c < 4; ++c) {
            short8 bs;
            #pragma unroll
            for (int j = 0; j < 8; ++j)
                ((u16*)&bs)[j] = f2bf(((const float*)&pb[j])[c]);
            int n = sBcb*4 + c;
            *(short8*)(lB + n*128 + ((16*sBkb) ^ ((n&7)<<4))) = bs;
        }
    };

    LOADA(0); LOADB(0);

    for (int it = 0; it < E_/64; ++it) {
        __syncthreads();
        WRITEA(); WRITEB();
        __syncthreads();
        if (it + 1 < E_/64) { LOADA((it+1)*64); LOADB((it+1)*64); }
        #pragma unroll
        for (int s = 0; s < 2; ++s) {
            short8 af[4], bfr[4];
            #pragma unroll
            for (int mt = 0; mt < 4; ++mt) {
                int row = wr*64 + mt*16 + q15;
                af[mt] = *(const short8*)(lA + row*128 + ((s*64 + 16*g) ^ ((row&7)<<4)));
            }
            #pragma unroll
            for (int nt = 0; nt < 4; ++nt) {
                int n = wc*64 + nt*16 + q15;
                bfr[nt] = *(const short8*)(lB + n*128 + ((s*64 + 16*g) ^ ((n&7)<<4)));
            }
            #pragma unroll
            for (int mt = 0; mt < 4; ++mt)
                #pragma unroll
                for (int nt = 0; nt < 4; ++nt)
                    acc[mt][nt] = __builtin_amdgcn_mfma_f32_16x16x32_bf16(
                        af[mt], bfr[nt], acc[mt][nt], 0, 0, 0);
        }
    }

    #pragma unroll
    for (int mt = 0; mt < 4; ++mt) {
        #pragma unroll
        for (int r = 0; r < 4; ++r) {
            int grow = by*128 + wr*64 + mt*16 + 4*g + r;
            if (MODE == 0) {
                int bb = grow >> 11, ss = grow & (S_-1);
                #pragma unroll
                for (int nt = 0; nt < 4; ++nt) {
                    int n = bx*128 + wc*64 + nt*16 + q15;
                    int hh = n >> 6, dd = n & 63;
                    ((u16*)Out)[(((size_t)bb*NH_ + hh)*S_ + ss)*DH_ + dd] =
                        f2bf(acc[mt][nt][r]);
                }
            } else {
                #pragma unroll
                for (int nt = 0; nt < 4; ++nt) {
                    int n = bx*128 + wc*64 + nt*16 + q15;
                    ((float*)Out)[(size_t)grow * F_ + n] = acc[mt][nt][r];
                }
            }
        }
    }
}

// ---------------------------------------------------------------------------
// V transpose: [b][h][s][d] -> Vt [b][h][d][s] (unchanged).
// ---------------------------------------------------------------------------
__global__ __launch_bounds__(256)
void vtrans(const u16* __restrict__ V, u16* __restrict__ Vt)
{
    __shared__ u16 t[64][66];
    const int tid = threadIdx.x;
    const int st  = blockIdx.x;
    const int bh  = blockIdx.y;

    {
        int s = tid >> 2, dseg = (tid & 3) * 16;
        const u16* src = V + ((size_t)bh*S_ + st*64 + s)*DH_ + dseg;
        short8 a = ((const short8*)src)[0];
        short8 b = ((const short8*)src)[1];
        *(short8*)&t[s][dseg]     = a;
        *(short8*)&t[s][dseg + 8] = b;
    }
    __syncthreads();
    {
        int d = tid >> 2, sseg = (tid & 3) * 16;
        short8 o0, o1;
        #pragma unroll
        for (int i = 0; i < 8; ++i) ((u16*)&o0)[i] = t[sseg + i][d];
        #pragma unroll
        for (int i = 0; i < 8; ++i) ((u16*)&o1)[i] = t[sseg + 8 + i][d];
        u16* dst = Vt + ((size_t)bh*DH_ + d)*S_ + st*64 + sseg;
        ((short8*)dst)[0] = o0;
        ((short8*)dst)[1] = o1;
    }
}

// ---------------------------------------------------------------------------
// MFMA flash attention v3: LDS V^T tile (staged from global V^T with
// ds_write_b128), swizzled b128 PV reads; per-wave P LDS; barriers per tile.
// ---------------------------------------------------------------------------
__global__ __launch_bounds__(256)
void attn_v3(const u16* Q, const u16* __restrict__ K,
             const u16* __restrict__ Vt, u16* O)
{
    __shared__ u16 vt[64*64];       // V^T tile [d][key], swizzled, 8 KB
    __shared__ u16 pl[4][16*64];    // per-wave P [q][key], swizzled, 8 KB

    const int tid  = threadIdx.x;
    const int lane = tid & 63;
    const int w    = tid >> 6;
    const int g    = lane >> 4;
    const int q15  = lane & 15;

    const int blk = blockIdx.x;
    const int tq  = blk & 31;
    const int qg  = (tq & 1) ? (31 - (tq >> 1)) : (tq >> 1);
    const int bh  = blk >> 5;
    const int q0  = qg * 64;

    const u16* Kb  = K  + (size_t)bh * S_ * DH_;
    const u16* Vtb = Vt + (size_t)bh * DH_ * S_;

    short8 qf0, qf1;
    {
        const u16* Qp = Q + ((size_t)bh * S_ + q0 + w*16 + q15) * DH_ + g*8;
        qf0 = *(const short8*)(Qp);
        qf1 = *(const short8*)(Qp + 32);
    }

    f32x4 o[4];
    #pragma unroll
    for (int dt = 0; dt < 4; ++dt) o[dt] = (f32x4){0.f,0.f,0.f,0.f};
    float mrow = -1e30f, lrow = 0.f;

    char* plw = (char*)&pl[w][0];
    const int sd = tid >> 2;           // staging d row 0..63
    const int sk = (tid & 3) * 32;     // staging key-chunk byte offset 0..96

    for (int kt = 0; kt <= qg; ++kt) {
        __syncthreads();
        // ---- stage V^T tile: coalesced global row read + 2x ds_write_b128 ----
        {
            const u16* vs = Vtb + (size_t)sd * S_ + kt*64 + (sk >> 1);
            short8 a = ((const short8*)vs)[0];
            short8 b = ((const short8*)vs)[1];
            char* dst = (char*)vt + sd*128;
            *(short8*)(dst + ((sk     ) ^ ((sd&7)<<4))) = a;
            *(short8*)(dst + ((sk + 16) ^ ((sd&7)<<4))) = b;
        }
        __syncthreads();

        // ---- QK^T: K frags from global (coalesced, L2-resident) ----
        float p[16];
        {
            const u16* Kp = Kb + (size_t)(kt*64 + q15) * DH_ + g*8;
            #pragma unroll
            for (int t = 0; t < 4; ++t) {
                f32x4 st = (f32x4){0.f,0.f,0.f,0.f};
                short8 kf0 = *(const short8*)(Kp + (size_t)t*16*DH_);
                short8 kf1 = *(const short8*)(Kp + (size_t)t*16*DH_ + 32);
                st = __builtin_amdgcn_mfma_f32_16x16x32_bf16(kf0, qf0, st, 0, 0, 0);
                st = __builtin_amdgcn_mfma_f32_16x16x32_bf16(kf1, qf1, st, 0, 0, 0);
                #pragma unroll
                for (int r = 0; r < 4; ++r) p[t*4+r] = st[r] * 0.125f;
            }
        }

        // causal mask (diagonal tile only)
        if (kt == qg) {
            #pragma unroll
            for (int t = 0; t < 4; ++t)
                #pragma unroll
                for (int r = 0; r < 4; ++r)
                    if (16*t + 4*g + r > w*16 + q15) p[t*4+r] = -1e30f;
        }

        // ---- online softmax ----
        float tmax = p[0];
        #pragma unroll
        for (int i = 1; i < 16; ++i) tmax = fmaxf(tmax, p[i]);
        tmax = fmaxf(tmax, __shfl_xor(tmax, 16));
        tmax = fmaxf(tmax, __shfl_xor(tmax, 32));
        float mnew = fmaxf(mrow, tmax);
        float rsc  = __expf(mrow - mnew);
        mrow = mnew;
        float psum = 0.f;
        #pragma unroll
        for (int i = 0; i < 16; ++i) { p[i] = __expf(p[i] - mnew); psum += p[i]; }
        psum += __shfl_xor(psum, 16);
        psum += __shfl_xor(psum, 32);
        lrow = lrow * rsc + psum;

        #pragma unroll
        for (int r = 0; r < 4; ++r) {
            float rr = __shfl(rsc, 4*g + r);
            #pragma unroll
            for (int dt = 0; dt < 4; ++dt) o[dt][r] *= rr;
        }

        // ---- P -> bf16 -> per-wave LDS ----
        #pragma unroll
        for (int t = 0; t < 4; ++t) {
            ushort4 pw;
            pw.x = f2bf(p[t*4+0]); pw.y = f2bf(p[t*4+1]);
            pw.z = f2bf(p[t*4+2]); pw.w = f2bf(p[t*4+3]);
            int byte = q15*128 + ((32*t + 8*g) ^ ((q15&7)<<4));
            *(ushort4*)(plw + byte) = pw;
        }

        // ---- PV: swizzled b128 LDS reads ----
        #pragma unroll
        for (int c = 0; c < 2; ++c) {
            int pb = q15*128 + ((64*c + 16*g) ^ ((q15&7)<<4));
            short8 pf = *(const short8*)(plw + pb);
            #pragma unroll
            for (int dt = 0; dt < 4; ++dt) {
                int d = dt*16 + q15;
                int vb = d*128 + ((64*c + 16*g) ^ ((d&7)<<4));
                short8 vf = *(const short8*)((char*)vt + vb);
                o[dt] = __builtin_amdgcn_mfma_f32_16x16x32_bf16(pf, vf, o[dt], 0, 0, 0);
            }
        }
    }

    // ---- epilogue ----
    float inv = 1.f / lrow;
    #pragma unroll
    for (int r = 0; r < 4; ++r) {
        float li = __shfl(inv, 4*g + r);
        int qrow = q0 + w*16 + 4*g + r;
        #pragma unroll
        for (int dt = 0; dt < 4; ++dt) {
            O[((size_t)bh * S_ + qrow) * DH_ + dt*16 + q15] = f2bf(o[dt][r] * li);
        }
    }
}

// ---------------------------------------------------------------------------
extern "C" void kernel_launch(void* const* d_in, const int* in_sizes, int n_in,
                              void* d_out, int out_size, void* d_ws, size_t ws_size,
                              hipStream_t stream) {
    (void)in_sizes; (void)n_in; (void)out_size; (void)ws_size;
    const float* x  = (const float*)d_in[0];
    const float* wq = (const float*)d_in[1];
    const float* wk = (const float*)d_in[2];
    const float* wv = (const float*)d_in[3];
    const float* wo = (const float*)d_in[4];

    u16* Qw = (u16*)d_ws;                    // [B][H][S][D] bf16 (O reuses)
    u16* Kw = Qw + (size_t)M_ * F_;
    u16* Vw = Kw + (size_t)M_ * F_;          // ws total 24 MiB
    u16* Vt = (u16*)d_out;                   // scratch; overwritten by oproj

    mfma_gemm<0><<<dim3(F_/128, M_/128, 3), 256, 0, stream>>>(
        (const void*)x, wq, wk, wv, (void*)Qw, (void*)Kw, (void*)Vw);
    vtrans<<<dim3(S_/64, B_*NH_), 256, 0, stream>>>(Vw, Vt);
    attn_v3<<<dim3(B_*NH_*(S_/64)), 256, 0, stream>>>(Qw, Kw, Vt, Qw);
    mfma_gemm<2><<<dim3(F_/128, M_/128, 1), 256, 0, stream>>>(
        (const void*)Qw, wo, wo, wo, d_out, d_out, d_out);
}